// Round 1
// 940.262 us; speedup vs baseline: 1.1494x; 1.1494x over previous
//
#include <hip/hip_runtime.h>
#include <math.h>

// Problem constants
#define BB 128
#define SS 64
#define EE 300
#define HH 512
#define LL 5
#define BSH (BB*SS*HH)   // 4,194,304
#define KP  320          // E padded to multiple of 32 for bf16 MFMA
#define NGRP 8           // chain-groups (16 chains each)
#define BPG  32          // blocks per group (h-slices of 16)
#define HSL  16          // h columns per block
#define WSROW 520        // LDS weight row stride (elems) -> 4-bank rotate
#define WS_BYTES (2*3*16*WSROW*2)   // 99,840 B dynamic LDS

typedef __attribute__((ext_vector_type(8))) short bf16x8;
typedef __attribute__((ext_vector_type(4))) float f32x4;
typedef __attribute__((ext_vector_type(4))) unsigned int u32x4;

__device__ __forceinline__ float fast_sigmoid(float x) {
    return 1.0f / (1.0f + __expf(-x));
}
__device__ __forceinline__ float fast_tanh(float x) {
    x = fminf(fmaxf(x, -20.0f), 20.0f);
    float e = __expf(2.0f * x);
    return (e - 1.0f) / (e + 1.0f);
}
__device__ __forceinline__ unsigned short f2bf(float f) {
    unsigned int u = __float_as_uint(f);
    u += 0x7fffu + ((u >> 16) & 1u);
    return (unsigned short)(u >> 16);
}
__device__ __forceinline__ float bf2f(unsigned short h) {
    return __uint_as_float((unsigned int)h << 16);
}
__device__ __forceinline__ void split2(float v, unsigned short& hi, unsigned short& lo) {
    hi = f2bf(v);
    lo = f2bf(v - bf2f(hi));
}

// Batched cross-XCD (LLC-coherent) 16-B load: sc0 sc1 bypasses L1+L2 so remote
// XCD stores (written through with sc0 sc1) are visible. Issued in bulk with a
// single manual vmcnt(0) drain -> one LLC round trip instead of 64.
#define LDX4(dst, addr, OFF) \
    asm volatile("global_load_dwordx4 %0, %1, off offset:" #OFF " sc0 sc1" \
                 : "=v"(dst) : "v"(addr))

#define STH(addr, val) \
    asm volatile("global_store_short %0, %1, off sc0 sc1" \
                 :: "v"(addr), "v"(val) : "memory")

// ---------------------------------------------------------------------------
// Prep: weight hi/lo splits, per-(b,t) active-children lists, zero barriers.
// ---------------------------------------------------------------------------
__global__ __launch_bounds__(256) void prep_kernel(
    const int* __restrict__ bfs, const int* __restrict__ children,
    const float* __restrict__ Wix, const float* __restrict__ Wfx, const float* __restrict__ Wux,
    const float* __restrict__ Wih, const float* __restrict__ Wfh, const float* __restrict__ Wuh,
    unsigned short* __restrict__ Wixh, unsigned short* __restrict__ Wixl,
    unsigned short* __restrict__ Wfxh, unsigned short* __restrict__ Wfxl,
    unsigned short* __restrict__ Wuxh, unsigned short* __restrict__ Wuxl,
    unsigned short* __restrict__ Wihh, unsigned short* __restrict__ Wihl,
    unsigned short* __restrict__ Wfhh, unsigned short* __restrict__ Wfhl,
    unsigned short* __restrict__ Wuhh, unsigned short* __restrict__ Wuhl,
    unsigned char* __restrict__ clist, int* __restrict__ ccnt, int* __restrict__ bars)
{
    const int gid = blockIdx.x * 256 + threadIdx.x;
    const int G = gridDim.x * 256;
    for (int i = gid; i < NGRP * SS; i += G) bars[i] = 0;
    for (int i = gid; i < 3 * HH * KP; i += G) {
        int g = i / (HH * KP), rem = i % (HH * KP), r = rem / KP, k = rem % KP;
        const float* src = (g == 0) ? Wix : (g == 1) ? Wfx : Wux;
        unsigned short* dh = (g == 0) ? Wixh : (g == 1) ? Wfxh : Wuxh;
        unsigned short* dl = (g == 0) ? Wixl : (g == 1) ? Wfxl : Wuxl;
        float v = (k < EE) ? src[(size_t)r * EE + k] : 0.0f;
        unsigned short hi, lo; split2(v, hi, lo);
        dh[r * KP + k] = hi; dl[r * KP + k] = lo;
    }
    for (int i = gid; i < 3 * HH * HH; i += G) {
        int g = i / (HH * HH), idx = i % (HH * HH);
        const float* src = (g == 0) ? Wih : (g == 1) ? Wfh : Wuh;
        unsigned short* dh = (g == 0) ? Wihh : (g == 1) ? Wfhh : Wuhh;
        unsigned short* dl = (g == 0) ? Wihl : (g == 1) ? Wfhl : Wuhl;
        unsigned short hi, lo; split2(src[idx], hi, lo);
        dh[idx] = hi; dl[idx] = lo;
    }
    if (gid < BB * SS) {
        const int b = gid >> 6, t = gid & 63;
        unsigned long long w = 0;
        for (int tp = 0; tp < t; ++tp) w |= 1ull << (bfs[b * SS + tp] & 63);
        const int cur = bfs[b * SS + t];
        const int* crow = children + (size_t)(b * SS + cur) * SS;
        unsigned char* lst = clist + (size_t)gid * SS;
        int cnt = 0;
        for (int s = 0; s < SS; ++s)
            if (crow[s] != 0 && ((w >> s) & 1ull)) lst[cnt++] = (unsigned char)s;
        ccnt[gid] = cnt;
    }
}

// ---------------------------------------------------------------------------
// XP precompute, split-bf16 MFMA -> PACKED output XPp[b*64+s][h][g] (g=0:i,1:f,2:u,
// slot3 unused). [8192 x 320] @ [320 x 512] per gate. M=16 tiles, grid (512,3).
// ---------------------------------------------------------------------------
__global__ __launch_bounds__(256) void xp_mfma(
    const int* __restrict__ x, const float* __restrict__ embed,
    const unsigned short* __restrict__ Wixh, const unsigned short* __restrict__ Wixl,
    const unsigned short* __restrict__ Wfxh, const unsigned short* __restrict__ Wfxl,
    const unsigned short* __restrict__ Wuxh, const unsigned short* __restrict__ Wuxl,
    const float* __restrict__ bix, const float* __restrict__ bih,
    const float* __restrict__ bfx, const float* __restrict__ bfh,
    const float* __restrict__ bux, const float* __restrict__ buh,
    float* __restrict__ XPp)
{
    const int mb = blockIdx.x;            // 512 tiles of 16 rows of B*S
    const int g  = blockIdx.y;            // gate
    const unsigned short* __restrict__ Wbh = (g == 0) ? Wixh : (g == 1) ? Wfxh : Wuxh;
    const unsigned short* __restrict__ Wbl = (g == 0) ? Wixl : (g == 1) ? Wfxl : Wuxl;
    const float* __restrict__ b1 = (g == 0) ? bix : (g == 1) ? bfx : bux;
    const float* __restrict__ b2 = (g == 0) ? bih : (g == 1) ? bfh : buh;

    const int row0 = mb * 16;
    __shared__ unsigned short As[2][16 * 328];
    __shared__ int toks[16];

    const int tid = threadIdx.x;
    if (tid < 16) toks[tid] = x[row0 + tid];
    __syncthreads();

    for (int i = tid; i < 16 * 75; i += 256) {
        int r = i / 75, c = i - r * 75;
        const float4 v = *(const float4*)(embed + (size_t)toks[r] * EE + c * 4);
        ushort4 hv, lv;
        split2(v.x, hv.x, lv.x); split2(v.y, hv.y, lv.y);
        split2(v.z, hv.z, lv.z); split2(v.w, hv.w, lv.w);
        *(ushort4*)&As[0][r * 328 + c * 4] = hv;
        *(ushort4*)&As[1][r * 328 + c * 4] = lv;
    }
    for (int i = tid; i < 16 * 20; i += 256) {
        int r = i / 20, k = EE + (i - r * 20);
        As[0][r * 328 + k] = 0; As[1][r * 328 + k] = 0;
    }
    __syncthreads();

    const int lane = tid & 63, wave = tid >> 6;
    const int quad = lane >> 4, col = lane & 15;
    const int wn = wave * 16;

    for (int nt = 0; nt < 8; ++nt) {
        const int gn = nt * 64 + wn + col;        // global output column
        const size_t wrow = (size_t)gn * KP;
        f32x4 accA = {0.f, 0.f, 0.f, 0.f}, accB = {0.f, 0.f, 0.f, 0.f};
        #pragma unroll
        for (int kq = 0; kq < 10; ++kq) {
            const int ka = kq * 32 + quad * 8;
            bf16x8 bh = *(const bf16x8*)(Wbh + wrow + ka);
            bf16x8 bl = *(const bf16x8*)(Wbl + wrow + ka);
            bf16x8 ah = *(const bf16x8*)&As[0][col * 328 + ka];
            bf16x8 al = *(const bf16x8*)&As[1][col * 328 + ka];
            accA = __builtin_amdgcn_mfma_f32_16x16x32_bf16(ah, bh, accA, 0, 0, 0);
            accB = __builtin_amdgcn_mfma_f32_16x16x32_bf16(ah, bl, accB, 0, 0, 0);
            accA = __builtin_amdgcn_mfma_f32_16x16x32_bf16(al, bh, accA, 0, 0, 0);
        }
        const f32x4 acc = accA + accB;
        const float bb = b1[gn] + b2[gn];
        #pragma unroll
        for (int reg = 0; reg < 4; ++reg) {
            const int ml = quad * 4 + reg;
            XPp[((size_t)(row0 + ml) * HH + gn) * 4 + g] = acc[reg] + bb;
        }
    }
}

// ---------------------------------------------------------------------------
// Fused recurrence v4: same topology as v3 (8 groups x 32 h-slice blocks,
// cooperative, one relaxed LLC group-barrier per step). Changes vs v3:
//  - h published as two bf16 planes (h_hi/h_lo) via 2-B sc0/sc1 stores
//    -> consumer needs no repack.
//  - proj reads h with 32 batched global_load_dwordx4 sc0 sc1 (inline asm),
//    ONE vmcnt(0) drain instead of 64 serialized 8-B agent-atomic loads.
//    (v3's VGPR_Count=64 forced the unrolled atomics into tiny wait-batches;
//    at 1 block/CU we have register headroom for the full 32-deep batch.)
//  - gates child-sum load pipeline deepened 4 -> 8.
// ---------------------------------------------------------------------------
__global__ __launch_bounds__(256, 1) void fused_steps(
    const int* __restrict__ bfs, const unsigned char* __restrict__ clist,
    const int* __restrict__ ccnt, const float* __restrict__ XPp,
    const unsigned short* __restrict__ Wihh, const unsigned short* __restrict__ Wihl,
    const unsigned short* __restrict__ Wfhh, const unsigned short* __restrict__ Wfhl,
    const unsigned short* __restrict__ Wuhh, const unsigned short* __restrict__ Wuhl,
    float* __restrict__ HWC, float* __restrict__ hf32,
    unsigned short* __restrict__ h_hi, unsigned short* __restrict__ h_lo,
    int* __restrict__ bars)
{
    extern __shared__ unsigned short Ws[];      // [plane2][gate3][16][WSROW]
    __shared__ int s_cur[16 * 64];              // bfs per (chain,t)
    __shared__ int s_cnt[16 * 64];              // child count per (chain,t)
    __shared__ unsigned char s_cl[16 * 64];     // child list for current step

    const int g = blockIdx.x & 7;               // group
    const int l = blockIdx.x >> 3;              // h-slice index 0..31
    const int tid = threadIdx.x;
    const int m0 = g * 16;                      // first chain of group
    const int n0 = l * HSL;                     // first h column of block

    const int lane = tid & 63, wave = tid >> 6;
    const int quad = lane >> 4, col = lane & 15;

    // gates task: one (chain, h) per thread
    const int chain = tid >> 4, hl = tid & 15;
    const int b = m0 + chain;
    const int h = n0 + hl;

    // ---- one-time init ----
    {   // weights: 2 planes x 3 gates x 16 rows x 64 16B-chunks = 6144 chunks
        for (int i = tid; i < 6144; i += 256) {
            const int plane = i / 3072, rem = i % 3072;
            const int gt = rem / 1024, rem2 = rem % 1024;
            const int r = rem2 >> 6, c = rem2 & 63;
            const unsigned short* src =
                (plane == 0) ? ((gt == 0) ? Wihh : (gt == 1) ? Wfhh : Wuhh)
                             : ((gt == 0) ? Wihl : (gt == 1) ? Wfhl : Wuhl);
            *(u32x4*)&Ws[((plane * 3 + gt) * 16 + r) * WSROW + c * 8] =
                *(const u32x4*)(src + (size_t)(n0 + r) * HH + c * 8);
        }
        for (int i = tid; i < 16 * 64; i += 256) {
            s_cur[i] = bfs[(m0 + (i >> 6)) * SS + (i & 63)];
            s_cnt[i] = ccnt[(m0 + (i >> 6)) * SS + (i & 63)];
        }
        if (tid < 64) {   // stage child list for t=0
            const int ch = tid >> 2, c = tid & 3;
            ((u32x4*)s_cl)[tid] =
                *(const u32x4*)(clist + ((size_t)(m0 + ch) * SS + 0) * SS + c * 16);
        }
    }
    __syncthreads();

    const size_t browf = (size_t)b * (SS * HH * 4);   // float offset of chain's HWC/XP rows
    float4 xp_c, xp_n;
    {
        const int cur0 = s_cur[(chain << 6) + 0];
        xp_c = *(const float4*)(XPp + browf + (size_t)cur0 * (HH * 4) + h * 4);
    }

    int* gbars = bars + g * SS;

    for (int t = 0; t < SS; ++t) {
        // ================= gates (all threads, 1 task) =================
        const int cur = s_cur[(chain << 6) + t];
        const int cnt = s_cnt[(chain << 6) + t];
        const float xpi = xp_c.x, xpf = xp_c.y, xpu = xp_c.z;
        const float* HWb = HWC + browf + h * 4;       // + child*2048
        const unsigned char* clp = &s_cl[chain << 6];

        float ai = 0.f, af = 0.f, au = 0.f, fc = 0.f;
        int idx = 0;
        while (idx + 8 <= cnt) {                       // 8-deep load pipeline
            const float4 v0 = *(const float4*)(HWb + (size_t)clp[idx + 0] * 2048);
            const float4 v1 = *(const float4*)(HWb + (size_t)clp[idx + 1] * 2048);
            const float4 v2 = *(const float4*)(HWb + (size_t)clp[idx + 2] * 2048);
            const float4 v3 = *(const float4*)(HWb + (size_t)clp[idx + 3] * 2048);
            const float4 v4 = *(const float4*)(HWb + (size_t)clp[idx + 4] * 2048);
            const float4 v5 = *(const float4*)(HWb + (size_t)clp[idx + 5] * 2048);
            const float4 v6 = *(const float4*)(HWb + (size_t)clp[idx + 6] * 2048);
            const float4 v7 = *(const float4*)(HWb + (size_t)clp[idx + 7] * 2048);
            ai += v0.x + v1.x + v2.x + v3.x + v4.x + v5.x + v6.x + v7.x;
            af += v0.y + v1.y + v2.y + v3.y + v4.y + v5.y + v6.y + v7.y;
            au += v0.z + v1.z + v2.z + v3.z + v4.z + v5.z + v6.z + v7.z;
            fc += fast_sigmoid(v0.y + xpf) * v0.w + fast_sigmoid(v1.y + xpf) * v1.w
                + fast_sigmoid(v2.y + xpf) * v2.w + fast_sigmoid(v3.y + xpf) * v3.w
                + fast_sigmoid(v4.y + xpf) * v4.w + fast_sigmoid(v5.y + xpf) * v5.w
                + fast_sigmoid(v6.y + xpf) * v6.w + fast_sigmoid(v7.y + xpf) * v7.w;
            idx += 8;
        }
        while (idx + 4 <= cnt) {
            const float4 v0 = *(const float4*)(HWb + (size_t)clp[idx + 0] * 2048);
            const float4 v1 = *(const float4*)(HWb + (size_t)clp[idx + 1] * 2048);
            const float4 v2 = *(const float4*)(HWb + (size_t)clp[idx + 2] * 2048);
            const float4 v3 = *(const float4*)(HWb + (size_t)clp[idx + 3] * 2048);
            ai += v0.x + v1.x + v2.x + v3.x;
            af += v0.y + v1.y + v2.y + v3.y;
            au += v0.z + v1.z + v2.z + v3.z;
            fc += fast_sigmoid(v0.y + xpf) * v0.w + fast_sigmoid(v1.y + xpf) * v1.w
                + fast_sigmoid(v2.y + xpf) * v2.w + fast_sigmoid(v3.y + xpf) * v3.w;
            idx += 4;
        }
        while (idx < cnt) {
            const float4 v = *(const float4*)(HWb + (size_t)clp[idx] * 2048);
            ai += v.x; af += v.y; au += v.z;
            fc += fast_sigmoid(v.y + xpf) * v.w;
            ++idx;
        }

        const float ig = fast_sigmoid(xpi + ai);
        const float og = fast_sigmoid(xpf + af);      // o shares fx/fh per source
        const float ug = fast_tanh(xpu + au);
        const float c  = ig * ug + fc;
        const float hv = og * fast_tanh(c);

        HWC[browf + (size_t)cur * 2048 + h * 4 + 3] = c;   // C slot (block-local)
        if (t == SS - 1) {
            hf32[(size_t)b * HH + h] = hv;
            break;
        }
        {   // publish h via cache-bypass stores (hi/lo planes, LLC-coherent)
            unsigned short hh_s, hlo_s; split2(hv, hh_s, hlo_s);
            const unsigned long long ah = (unsigned long long)(h_hi + (size_t)b * HH + h);
            const unsigned long long al = (unsigned long long)(h_lo + (size_t)b * HH + h);
            STH(ah, (unsigned int)hh_s);
            STH(al, (unsigned int)hlo_s);
        }
        // prefetch next step's XP (latency hidden behind barrier)
        {
            const int curn = s_cur[(chain << 6) + t + 1];
            xp_n = *(const float4*)(XPp + browf + (size_t)curn * (HH * 4) + h * 4);
        }

        // ============ one relaxed group barrier (h visibility) ============
        __asm__ volatile("s_waitcnt vmcnt(0)" ::: "memory");  // drain h stores
        __syncthreads();
        if (tid == 0) {
            int* cntp = gbars + t;
            __hip_atomic_fetch_add(cntp, 1, __ATOMIC_RELAXED, __HIP_MEMORY_SCOPE_AGENT);
            while (__hip_atomic_load(cntp, __ATOMIC_RELAXED, __HIP_MEMORY_SCOPE_AGENT) < BPG)
                __builtin_amdgcn_s_sleep(1);
        }
        __syncthreads();

        // ================= proj (waves 0-2) / service (wave 3) =============
        if (wave < 3) {
            // Each lane consumes the full 512-wide h row of chain (m0+col):
            // elements ka = kq*32 + quad*8 .. +8, kq = 0..15.
            const size_t hbase = (size_t)(m0 + col) * HH;
            const unsigned long long hb =
                (unsigned long long)(h_hi + hbase + quad * 8);
            const unsigned long long lb =
                (unsigned long long)(h_lo + hbase + quad * 8);
            bf16x8 hhv[16], hlv[16];
            LDX4(hhv[ 0], hb,   0); LDX4(hhv[ 1], hb,  64);
            LDX4(hhv[ 2], hb, 128); LDX4(hhv[ 3], hb, 192);
            LDX4(hhv[ 4], hb, 256); LDX4(hhv[ 5], hb, 320);
            LDX4(hhv[ 6], hb, 384); LDX4(hhv[ 7], hb, 448);
            LDX4(hhv[ 8], hb, 512); LDX4(hhv[ 9], hb, 576);
            LDX4(hhv[10], hb, 640); LDX4(hhv[11], hb, 704);
            LDX4(hhv[12], hb, 768); LDX4(hhv[13], hb, 832);
            LDX4(hhv[14], hb, 896); LDX4(hhv[15], hb, 960);
            LDX4(hlv[ 0], lb,   0); LDX4(hlv[ 1], lb,  64);
            LDX4(hlv[ 2], lb, 128); LDX4(hlv[ 3], lb, 192);
            LDX4(hlv[ 4], lb, 256); LDX4(hlv[ 5], lb, 320);
            LDX4(hlv[ 6], lb, 384); LDX4(hlv[ 7], lb, 448);
            LDX4(hlv[ 8], lb, 512); LDX4(hlv[ 9], lb, 576);
            LDX4(hlv[10], lb, 640); LDX4(hlv[11], lb, 704);
            LDX4(hlv[12], lb, 768); LDX4(hlv[13], lb, 832);
            LDX4(hlv[14], lb, 896); LDX4(hlv[15], lb, 960);
            asm volatile("s_waitcnt vmcnt(0)" ::: "memory");
            __builtin_amdgcn_sched_barrier(0);   // keep uses below the drain

            f32x4 accA = {0.f, 0.f, 0.f, 0.f}, accB = {0.f, 0.f, 0.f, 0.f};
            #pragma unroll
            for (int kq = 0; kq < 16; ++kq) {
                const int ka = kq * 32 + quad * 8;
                bf16x8 bh = *(const bf16x8*)&Ws[((0 * 3 + wave) * 16 + col) * WSROW + ka];
                bf16x8 bl = *(const bf16x8*)&Ws[((1 * 3 + wave) * 16 + col) * WSROW + ka];
                accA = __builtin_amdgcn_mfma_f32_16x16x32_bf16(hhv[kq], bh, accA, 0, 0, 0);
                accB = __builtin_amdgcn_mfma_f32_16x16x32_bf16(hhv[kq], bl, accB, 0, 0, 0);
                accA = __builtin_amdgcn_mfma_f32_16x16x32_bf16(hlv[kq], bh, accA, 0, 0, 0);
            }
            const f32x4 acc = accA + accB;
            // scatter: D col=lane&15 -> W-row j (h col n0+j); row quad*4+reg -> chain
            #pragma unroll
            for (int reg = 0; reg < 4; ++reg) {
                const int m = quad * 4 + reg;
                const int curm = s_cur[(m << 6) + t];
                HWC[(size_t)(m0 + m) * (SS * HH * 4) + (size_t)curm * 2048
                    + (n0 + col) * 4 + wave] = acc[reg];
            }
        } else {
            // stage child lists for step t+1
            if (lane < 64) {
                const int ch = lane >> 2, cc = lane & 3;
                ((u32x4*)s_cl)[lane] =
                    *(const u32x4*)(clist + ((size_t)(m0 + ch) * SS + (t + 1)) * SS + cc * 16);
            }
        }
        __threadfence_block();      // proj scatter -> next gates (same block)
        __syncthreads();
        xp_c = xp_n;
    }
}

// ---------------------------------------------------------------------------
// Final projection: out[b,l] = hf32[b,:] . Wout[l,:] + bout[l]
// ---------------------------------------------------------------------------
__global__ __launch_bounds__(64) void out_kernel(
    const float* __restrict__ hcur,
    const float* __restrict__ Wout, const float* __restrict__ bout,
    float* __restrict__ out)
{
    const int b = blockIdx.x;
    const int lane = threadIdx.x;
    float acc[LL];
    #pragma unroll
    for (int l = 0; l < LL; ++l) acc[l] = 0.0f;
    for (int h = lane; h < HH; h += 64) {
        const float hv = hcur[(size_t)b * HH + h];
        #pragma unroll
        for (int l = 0; l < LL; ++l) acc[l] += hv * Wout[l * HH + h];
    }
    #pragma unroll
    for (int off = 32; off > 0; off >>= 1) {
        #pragma unroll
        for (int l = 0; l < LL; ++l) acc[l] += __shfl_down(acc[l], off);
    }
    if (lane == 0) {
        #pragma unroll
        for (int l = 0; l < LL; ++l) out[b * LL + l] = acc[l] + bout[l];
    }
}

extern "C" void kernel_launch(void* const* d_in, const int* in_sizes, int n_in,
                              void* d_out, int out_size, void* d_ws, size_t ws_size,
                              hipStream_t stream)
{
    (void)in_sizes; (void)n_in; (void)out_size; (void)ws_size;
    const int*   x        = (const int*)d_in[0];
    const int*   bfs      = (const int*)d_in[1];
    const int*   children = (const int*)d_in[2];
    const float* embed    = (const float*)d_in[3];
    const float* Wix = (const float*)d_in[4];
    const float* bix = (const float*)d_in[5];
    const float* Wih = (const float*)d_in[6];
    const float* bih = (const float*)d_in[7];
    const float* Wfx = (const float*)d_in[8];
    const float* bfx = (const float*)d_in[9];
    const float* Wfh = (const float*)d_in[10];
    const float* bfh = (const float*)d_in[11];
    const float* Wux = (const float*)d_in[12];
    const float* bux = (const float*)d_in[13];
    const float* Wuh = (const float*)d_in[14];
    const float* buh = (const float*)d_in[15];
    const float* Wout = (const float*)d_in[16];
    const float* bout = (const float*)d_in[17];
    float* out = (float*)d_out;

    // Workspace (~141 MB)
    char* p = (char*)d_ws;
    float* XPp = (float*)p;            p += (size_t)BSH * 4 * 4;   // packed i,f,u,pad
    float* HWC = (float*)p;            p += (size_t)BSH * 4 * 4;   // packed HWi,HWf,HWu,C
    float* hf32 = (float*)p;           p += (size_t)BB * HH * 4;
    unsigned short* h_hi = (unsigned short*)p; p += (size_t)BB * HH * 2;
    unsigned short* h_lo = (unsigned short*)p; p += (size_t)BB * HH * 2;
    unsigned short* Wixh = (unsigned short*)p; p += (size_t)HH * KP * 2;
    unsigned short* Wixl = (unsigned short*)p; p += (size_t)HH * KP * 2;
    unsigned short* Wfxh = (unsigned short*)p; p += (size_t)HH * KP * 2;
    unsigned short* Wfxl = (unsigned short*)p; p += (size_t)HH * KP * 2;
    unsigned short* Wuxh = (unsigned short*)p; p += (size_t)HH * KP * 2;
    unsigned short* Wuxl = (unsigned short*)p; p += (size_t)HH * KP * 2;
    unsigned short* Wihh = (unsigned short*)p; p += (size_t)HH * HH * 2;
    unsigned short* Wihl = (unsigned short*)p; p += (size_t)HH * HH * 2;
    unsigned short* Wfhh = (unsigned short*)p; p += (size_t)HH * HH * 2;
    unsigned short* Wfhl = (unsigned short*)p; p += (size_t)HH * HH * 2;
    unsigned short* Wuhh = (unsigned short*)p; p += (size_t)HH * HH * 2;
    unsigned short* Wuhl = (unsigned short*)p; p += (size_t)HH * HH * 2;
    unsigned char* clist = (unsigned char*)p;  p += (size_t)BB * SS * SS;
    int* ccnt = (int*)p;               p += (size_t)BB * SS * 4;
    int* bars = (int*)p;               p += (size_t)NGRP * SS * 4;

    (void)hipFuncSetAttribute((const void*)fused_steps,
                              hipFuncAttributeMaxDynamicSharedMemorySize,
                              WS_BYTES);

    prep_kernel<<<dim3(256), 256, 0, stream>>>(
        bfs, children, Wix, Wfx, Wux, Wih, Wfh, Wuh,
        Wixh, Wixl, Wfxh, Wfxl, Wuxh, Wuxl,
        Wihh, Wihl, Wfhh, Wfhl, Wuhh, Wuhl, clist, ccnt, bars);

    xp_mfma<<<dim3(512, 3), 256, 0, stream>>>(
        x, embed, Wixh, Wixl, Wfxh, Wfxl, Wuxh, Wuxl,
        bix, bih, bfx, bfh, bux, buh, XPp);

    {
        void* args[] = {
            (void*)&bfs, (void*)&clist, (void*)&ccnt, (void*)&XPp,
            (void*)&Wihh, (void*)&Wihl, (void*)&Wfhh, (void*)&Wfhl,
            (void*)&Wuhh, (void*)&Wuhl,
            (void*)&HWC, (void*)&hf32, (void*)&h_hi, (void*)&h_lo, (void*)&bars
        };
        hipLaunchCooperativeKernel((void*)fused_steps, dim3(NGRP * BPG), dim3(256),
                                   args, WS_BYTES, stream);
    }

    out_kernel<<<dim3(BB), 64, 0, stream>>>(hf32, Wout, bout, out);
}

// Round 5
// 824.265 us; speedup vs baseline: 1.3112x; 1.1407x over previous
//
#include <hip/hip_runtime.h>
#include <math.h>

// Problem constants
#define BB 128
#define SS 64
#define EE 300
#define HH 512
#define LL 5
#define BSH (BB*SS*HH)   // 4,194,304
#define KP  320          // E padded to multiple of 32 for bf16 MFMA
#define NGRP 8           // chain-groups (16 chains each)
#define BPG  32          // blocks per group (h-slices of 16)
#define HSL  16          // h columns per block
#define WSROW 520        // LDS weight row stride (elems) -> 4-bank rotate
#define HS_BASE (2*3*16*WSROW)            // 49,920 hw: start of staged-h region
#define WS_BYTES ((2*3*16*WSROW + 2*16*WSROW)*2)   // 133,120 B dynamic LDS

typedef __attribute__((ext_vector_type(8))) short bf16x8;
typedef __attribute__((ext_vector_type(4))) float f32x4;
typedef __attribute__((ext_vector_type(4))) unsigned int u32x4;

__device__ __forceinline__ float fast_sigmoid(float x) {
    return 1.0f / (1.0f + __expf(-x));
}
__device__ __forceinline__ float fast_tanh(float x) {
    x = fminf(fmaxf(x, -20.0f), 20.0f);
    float e = __expf(2.0f * x);
    return (e - 1.0f) / (e + 1.0f);
}
__device__ __forceinline__ unsigned short f2bf(float f) {
    unsigned int u = __float_as_uint(f);
    u += 0x7fffu + ((u >> 16) & 1u);
    return (unsigned short)(u >> 16);
}
__device__ __forceinline__ float bf2f(unsigned short h) {
    return __uint_as_float((unsigned int)h << 16);
}
__device__ __forceinline__ void split2(float v, unsigned short& hi, unsigned short& lo) {
    hi = f2bf(v);
    lo = f2bf(v - bf2f(hi));
}

// LLC-coherent (cross-XCD) 16-B load: sc0 sc1 bypasses L1+L2 so remote XCD
// write-through stores are visible.
#define LDX4V(dst, addr) \
    asm volatile("global_load_dwordx4 %0, %1, off sc0 sc1" \
                 : "=v"(dst) : "v"(addr))

#define STH(addr, val) \
    asm volatile("global_store_short %0, %1, off sc0 sc1" \
                 :: "v"(addr), "v"(val) : "memory")

// ---------------------------------------------------------------------------
// Prep: weight hi/lo splits, per-(b,t) active-children lists, zero barriers.
// ---------------------------------------------------------------------------
__global__ __launch_bounds__(256) void prep_kernel(
    const int* __restrict__ bfs, const int* __restrict__ children,
    const float* __restrict__ Wix, const float* __restrict__ Wfx, const float* __restrict__ Wux,
    const float* __restrict__ Wih, const float* __restrict__ Wfh, const float* __restrict__ Wuh,
    unsigned short* __restrict__ Wixh, unsigned short* __restrict__ Wixl,
    unsigned short* __restrict__ Wfxh, unsigned short* __restrict__ Wfxl,
    unsigned short* __restrict__ Wuxh, unsigned short* __restrict__ Wuxl,
    unsigned short* __restrict__ Wihh, unsigned short* __restrict__ Wihl,
    unsigned short* __restrict__ Wfhh, unsigned short* __restrict__ Wfhl,
    unsigned short* __restrict__ Wuhh, unsigned short* __restrict__ Wuhl,
    unsigned char* __restrict__ clist, int* __restrict__ ccnt, int* __restrict__ bars)
{
    const int gid = blockIdx.x * 256 + threadIdx.x;
    const int G = gridDim.x * 256;
    for (int i = gid; i < NGRP * SS; i += G) bars[i] = 0;
    for (int i = gid; i < 3 * HH * KP; i += G) {
        int g = i / (HH * KP), rem = i % (HH * KP), r = rem / KP, k = rem % KP;
        const float* src = (g == 0) ? Wix : (g == 1) ? Wfx : Wux;
        unsigned short* dh = (g == 0) ? Wixh : (g == 1) ? Wfxh : Wuxh;
        unsigned short* dl = (g == 0) ? Wixl : (g == 1) ? Wfxl : Wuxl;
        float v = (k < EE) ? src[(size_t)r * EE + k] : 0.0f;
        unsigned short hi, lo; split2(v, hi, lo);
        dh[r * KP + k] = hi; dl[r * KP + k] = lo;
    }
    for (int i = gid; i < 3 * HH * HH; i += G) {
        int g = i / (HH * HH), idx = i % (HH * HH);
        const float* src = (g == 0) ? Wih : (g == 1) ? Wfh : Wuh;
        unsigned short* dh = (g == 0) ? Wihh : (g == 1) ? Wfhh : Wuhh;
        unsigned short* dl = (g == 0) ? Wihl : (g == 1) ? Wfhl : Wuhl;
        unsigned short hi, lo; split2(src[idx], hi, lo);
        dh[idx] = hi; dl[idx] = lo;
    }
    if (gid < BB * SS) {
        const int b = gid >> 6, t = gid & 63;
        unsigned long long w = 0;
        for (int tp = 0; tp < t; ++tp) w |= 1ull << (bfs[b * SS + tp] & 63);
        const int cur = bfs[b * SS + t];
        const int* crow = children + (size_t)(b * SS + cur) * SS;
        unsigned char* lst = clist + (size_t)gid * SS;
        int cnt = 0;
        for (int s = 0; s < SS; ++s)
            if (crow[s] != 0 && ((w >> s) & 1ull)) lst[cnt++] = (unsigned char)s;
        ccnt[gid] = cnt;
    }
}

// ---------------------------------------------------------------------------
// XP precompute, split-bf16 MFMA -> PACKED output XPp[b*64+s][h][g] (g=0:i,1:f,2:u,
// slot3 unused). [8192 x 320] @ [320 x 512] per gate. M=16 tiles, grid (512,3).
// ---------------------------------------------------------------------------
__global__ __launch_bounds__(256) void xp_mfma(
    const int* __restrict__ x, const float* __restrict__ embed,
    const unsigned short* __restrict__ Wixh, const unsigned short* __restrict__ Wixl,
    const unsigned short* __restrict__ Wfxh, const unsigned short* __restrict__ Wfxl,
    const unsigned short* __restrict__ Wuxh, const unsigned short* __restrict__ Wuxl,
    const float* __restrict__ bix, const float* __restrict__ bih,
    const float* __restrict__ bfx, const float* __restrict__ bfh,
    const float* __restrict__ bux, const float* __restrict__ buh,
    float* __restrict__ XPp)
{
    const int mb = blockIdx.x;            // 512 tiles of 16 rows of B*S
    const int g  = blockIdx.y;            // gate
    const unsigned short* __restrict__ Wbh = (g == 0) ? Wixh : (g == 1) ? Wfxh : Wuxh;
    const unsigned short* __restrict__ Wbl = (g == 0) ? Wixl : (g == 1) ? Wfxl : Wuxl;
    const float* __restrict__ b1 = (g == 0) ? bix : (g == 1) ? bfx : bux;
    const float* __restrict__ b2 = (g == 0) ? bih : (g == 1) ? bfh : buh;

    const int row0 = mb * 16;
    __shared__ unsigned short As[2][16 * 328];
    __shared__ int toks[16];

    const int tid = threadIdx.x;
    if (tid < 16) toks[tid] = x[row0 + tid];
    __syncthreads();

    for (int i = tid; i < 16 * 75; i += 256) {
        int r = i / 75, c = i - r * 75;
        const float4 v = *(const float4*)(embed + (size_t)toks[r] * EE + c * 4);
        ushort4 hv, lv;
        split2(v.x, hv.x, lv.x); split2(v.y, hv.y, lv.y);
        split2(v.z, hv.z, lv.z); split2(v.w, hv.w, lv.w);
        *(ushort4*)&As[0][r * 328 + c * 4] = hv;
        *(ushort4*)&As[1][r * 328 + c * 4] = lv;
    }
    for (int i = tid; i < 16 * 20; i += 256) {
        int r = i / 20, k = EE + (i - r * 20);
        As[0][r * 328 + k] = 0; As[1][r * 328 + k] = 0;
    }
    __syncthreads();

    const int lane = tid & 63, wave = tid >> 6;
    const int quad = lane >> 4, col = lane & 15;
    const int wn = wave * 16;

    for (int nt = 0; nt < 8; ++nt) {
        const int gn = nt * 64 + wn + col;        // global output column
        const size_t wrow = (size_t)gn * KP;
        f32x4 accA = {0.f, 0.f, 0.f, 0.f}, accB = {0.f, 0.f, 0.f, 0.f};
        #pragma unroll
        for (int kq = 0; kq < 10; ++kq) {
            const int ka = kq * 32 + quad * 8;
            bf16x8 bh = *(const bf16x8*)(Wbh + wrow + ka);
            bf16x8 bl = *(const bf16x8*)(Wbl + wrow + ka);
            bf16x8 ah = *(const bf16x8*)&As[0][col * 328 + ka];
            bf16x8 al = *(const bf16x8*)&As[1][col * 328 + ka];
            accA = __builtin_amdgcn_mfma_f32_16x16x32_bf16(ah, bh, accA, 0, 0, 0);
            accB = __builtin_amdgcn_mfma_f32_16x16x32_bf16(ah, bl, accB, 0, 0, 0);
            accA = __builtin_amdgcn_mfma_f32_16x16x32_bf16(al, bh, accA, 0, 0, 0);
        }
        const f32x4 acc = accA + accB;
        const float bb = b1[gn] + b2[gn];
        #pragma unroll
        for (int reg = 0; reg < 4; ++reg) {
            const int ml = quad * 4 + reg;
            XPp[((size_t)(row0 + ml) * HH + gn) * 4 + g] = acc[reg] + bb;
        }
    }
}

// ---------------------------------------------------------------------------
// Fused recurrence v8 = v4 (proven protocol, byte-for-byte sync structure)
// + LDS h-broadcast: after the rendezvous, all 4 waves cooperatively stage
// the group's 16 chains x 512 h (hi+lo planes, 32 KB) into LDS ONCE via
// 8x 16-B sc0/sc1 loads per thread (32 VGPRs in flight -> no spill hazard),
// then the 3 proj waves read MFMA A-fragments from LDS. Cuts LLC-bypass
// traffic 3x (was 96 KB/block/step: each proj wave redundantly loaded the
// same 32 KB).
// ---------------------------------------------------------------------------
__global__ __launch_bounds__(256, 1) void fused_steps(
    const int* __restrict__ bfs, const unsigned char* __restrict__ clist,
    const int* __restrict__ ccnt, const float* __restrict__ XPp,
    const unsigned short* __restrict__ Wihh, const unsigned short* __restrict__ Wihl,
    const unsigned short* __restrict__ Wfhh, const unsigned short* __restrict__ Wfhl,
    const unsigned short* __restrict__ Wuhh, const unsigned short* __restrict__ Wuhl,
    float* __restrict__ HWC, float* __restrict__ hf32,
    unsigned short* __restrict__ h_hi, unsigned short* __restrict__ h_lo,
    int* __restrict__ bars)
{
    extern __shared__ unsigned short Ws[];      // [plane2][gate3][16][WSROW] + Hs[2][16][WSROW]
    __shared__ int s_cur[16 * 64];              // bfs per (chain,t)
    __shared__ int s_cnt[16 * 64];              // child count per (chain,t)
    __shared__ unsigned char s_cl[16 * 64];     // child list for current step

    const int g = blockIdx.x & 7;               // group
    const int l = blockIdx.x >> 3;              // h-slice index 0..31
    const int tid = threadIdx.x;
    const int m0 = g * 16;                      // first chain of group
    const int n0 = l * HSL;                     // first h column of block

    const int lane = tid & 63, wave = tid >> 6;
    const int quad = lane >> 4, col = lane & 15;

    // gates task: one (chain, h) per thread
    const int chain = tid >> 4, hl = tid & 15;
    const int b = m0 + chain;
    const int h = n0 + hl;

    // ---- one-time init ----
    {   // weights: 2 planes x 3 gates x 16 rows x 64 16B-chunks = 6144 chunks
        for (int i = tid; i < 6144; i += 256) {
            const int plane = i / 3072, rem = i % 3072;
            const int gt = rem / 1024, rem2 = rem % 1024;
            const int r = rem2 >> 6, c = rem2 & 63;
            const unsigned short* src =
                (plane == 0) ? ((gt == 0) ? Wihh : (gt == 1) ? Wfhh : Wuhh)
                             : ((gt == 0) ? Wihl : (gt == 1) ? Wfhl : Wuhl);
            *(u32x4*)&Ws[((plane * 3 + gt) * 16 + r) * WSROW + c * 8] =
                *(const u32x4*)(src + (size_t)(n0 + r) * HH + c * 8);
        }
        for (int i = tid; i < 16 * 64; i += 256) {
            s_cur[i] = bfs[(m0 + (i >> 6)) * SS + (i & 63)];
            s_cnt[i] = ccnt[(m0 + (i >> 6)) * SS + (i & 63)];
        }
        if (tid < 64) {   // stage child list for t=0
            const int ch = tid >> 2, c = tid & 3;
            ((u32x4*)s_cl)[tid] =
                *(const u32x4*)(clist + ((size_t)(m0 + ch) * SS + 0) * SS + c * 16);
        }
    }
    __syncthreads();

    const size_t browf = (size_t)b * (SS * HH * 4);   // float offset of chain's HWC/XP rows
    float4 xp_c, xp_n;
    {
        const int cur0 = s_cur[(chain << 6) + 0];
        xp_c = *(const float4*)(XPp + browf + (size_t)cur0 * (HH * 4) + h * 4);
    }

    int* gbars = bars + g * SS;

    // per-thread staging chunk mapping (constant over steps):
    // chunk i = j*256 + tid, i in [0,2048): plane p = i>>10, chain ch = (i&1023)>>6,
    // 16B-chunk o16 = i&63 -> h offset o16*8.
    int st_p[8], st_ch[8], st_o16[8];
    #pragma unroll
    for (int j = 0; j < 8; ++j) {
        const int i = j * 256 + tid;
        st_p[j] = i >> 10; st_ch[j] = (i & 1023) >> 6; st_o16[j] = i & 63;
    }

    for (int t = 0; t < SS; ++t) {
        // ================= gates (all threads, 1 task) =================
        const int cur = s_cur[(chain << 6) + t];
        const int cnt = s_cnt[(chain << 6) + t];
        const float xpi = xp_c.x, xpf = xp_c.y, xpu = xp_c.z;
        const float* HWb = HWC + browf + h * 4;       // + child*2048
        const unsigned char* clp = &s_cl[chain << 6];

        float ai = 0.f, af = 0.f, au = 0.f, fc = 0.f;
        int idx = 0;
        while (idx + 8 <= cnt) {                       // 8-deep load pipeline
            const float4 v0 = *(const float4*)(HWb + (size_t)clp[idx + 0] * 2048);
            const float4 v1 = *(const float4*)(HWb + (size_t)clp[idx + 1] * 2048);
            const float4 v2 = *(const float4*)(HWb + (size_t)clp[idx + 2] * 2048);
            const float4 v3 = *(const float4*)(HWb + (size_t)clp[idx + 3] * 2048);
            const float4 v4 = *(const float4*)(HWb + (size_t)clp[idx + 4] * 2048);
            const float4 v5 = *(const float4*)(HWb + (size_t)clp[idx + 5] * 2048);
            const float4 v6 = *(const float4*)(HWb + (size_t)clp[idx + 6] * 2048);
            const float4 v7 = *(const float4*)(HWb + (size_t)clp[idx + 7] * 2048);
            ai += v0.x + v1.x + v2.x + v3.x + v4.x + v5.x + v6.x + v7.x;
            af += v0.y + v1.y + v2.y + v3.y + v4.y + v5.y + v6.y + v7.y;
            au += v0.z + v1.z + v2.z + v3.z + v4.z + v5.z + v6.z + v7.z;
            fc += fast_sigmoid(v0.y + xpf) * v0.w + fast_sigmoid(v1.y + xpf) * v1.w
                + fast_sigmoid(v2.y + xpf) * v2.w + fast_sigmoid(v3.y + xpf) * v3.w
                + fast_sigmoid(v4.y + xpf) * v4.w + fast_sigmoid(v5.y + xpf) * v5.w
                + fast_sigmoid(v6.y + xpf) * v6.w + fast_sigmoid(v7.y + xpf) * v7.w;
            idx += 8;
        }
        while (idx + 4 <= cnt) {
            const float4 v0 = *(const float4*)(HWb + (size_t)clp[idx + 0] * 2048);
            const float4 v1 = *(const float4*)(HWb + (size_t)clp[idx + 1] * 2048);
            const float4 v2 = *(const float4*)(HWb + (size_t)clp[idx + 2] * 2048);
            const float4 v3 = *(const float4*)(HWb + (size_t)clp[idx + 3] * 2048);
            ai += v0.x + v1.x + v2.x + v3.x;
            af += v0.y + v1.y + v2.y + v3.y;
            au += v0.z + v1.z + v2.z + v3.z;
            fc += fast_sigmoid(v0.y + xpf) * v0.w + fast_sigmoid(v1.y + xpf) * v1.w
                + fast_sigmoid(v2.y + xpf) * v2.w + fast_sigmoid(v3.y + xpf) * v3.w;
            idx += 4;
        }
        while (idx < cnt) {
            const float4 v = *(const float4*)(HWb + (size_t)clp[idx] * 2048);
            ai += v.x; af += v.y; au += v.z;
            fc += fast_sigmoid(v.y + xpf) * v.w;
            ++idx;
        }

        const float ig = fast_sigmoid(xpi + ai);
        const float og = fast_sigmoid(xpf + af);      // o shares fx/fh per source
        const float ug = fast_tanh(xpu + au);
        const float c  = ig * ug + fc;
        const float hv = og * fast_tanh(c);

        HWC[browf + (size_t)cur * 2048 + h * 4 + 3] = c;   // C slot (block-local)
        if (t == SS - 1) {
            hf32[(size_t)b * HH + h] = hv;
            break;
        }
        {   // publish h via cache-bypass stores (hi/lo planes, LLC-coherent)
            unsigned short hh_s, hlo_s; split2(hv, hh_s, hlo_s);
            const unsigned long long ah = (unsigned long long)(h_hi + (size_t)b * HH + h);
            const unsigned long long al = (unsigned long long)(h_lo + (size_t)b * HH + h);
            STH(ah, (unsigned int)hh_s);
            STH(al, (unsigned int)hlo_s);
        }
        // prefetch next step's XP (latency hidden behind barrier)
        {
            const int curn = s_cur[(chain << 6) + t + 1];
            xp_n = *(const float4*)(XPp + browf + (size_t)curn * (HH * 4) + h * 4);
        }

        // ============ one relaxed group barrier (h visibility) ============
        __asm__ volatile("s_waitcnt vmcnt(0)" ::: "memory");  // drain h stores
        __syncthreads();                                      // (1)
        if (tid == 0) {
            int* cntp = gbars + t;
            __hip_atomic_fetch_add(cntp, 1, __ATOMIC_RELAXED, __HIP_MEMORY_SCOPE_AGENT);
            while (__hip_atomic_load(cntp, __ATOMIC_RELAXED, __HIP_MEMORY_SCOPE_AGENT) < BPG)
                __builtin_amdgcn_s_sleep(1);
        }
        __syncthreads();                                      // (2) all h published

        // ====== cooperative h staging: LLC -> LDS, once per block ======
        if (wave == 3 && lane < 64) {
            // service: stage child lists for step t+1 (cached loads)
            const int ch = lane >> 2, cc = lane & 3;
            ((u32x4*)s_cl)[lane] =
                *(const u32x4*)(clist + ((size_t)(m0 + ch) * SS + (t + 1)) * SS + cc * 16);
        }
        {
            u32x4 st0, st1, st2, st3, st4, st5, st6, st7;
            const unsigned long long a0 = (unsigned long long)((st_p[0] ? h_lo : h_hi) + (size_t)(m0 + st_ch[0]) * HH + st_o16[0] * 8);
            const unsigned long long a1 = (unsigned long long)((st_p[1] ? h_lo : h_hi) + (size_t)(m0 + st_ch[1]) * HH + st_o16[1] * 8);
            const unsigned long long a2 = (unsigned long long)((st_p[2] ? h_lo : h_hi) + (size_t)(m0 + st_ch[2]) * HH + st_o16[2] * 8);
            const unsigned long long a3 = (unsigned long long)((st_p[3] ? h_lo : h_hi) + (size_t)(m0 + st_ch[3]) * HH + st_o16[3] * 8);
            const unsigned long long a4 = (unsigned long long)((st_p[4] ? h_lo : h_hi) + (size_t)(m0 + st_ch[4]) * HH + st_o16[4] * 8);
            const unsigned long long a5 = (unsigned long long)((st_p[5] ? h_lo : h_hi) + (size_t)(m0 + st_ch[5]) * HH + st_o16[5] * 8);
            const unsigned long long a6 = (unsigned long long)((st_p[6] ? h_lo : h_hi) + (size_t)(m0 + st_ch[6]) * HH + st_o16[6] * 8);
            const unsigned long long a7 = (unsigned long long)((st_p[7] ? h_lo : h_hi) + (size_t)(m0 + st_ch[7]) * HH + st_o16[7] * 8);
            LDX4V(st0, a0); LDX4V(st1, a1); LDX4V(st2, a2); LDX4V(st3, a3);
            LDX4V(st4, a4); LDX4V(st5, a5); LDX4V(st6, a6); LDX4V(st7, a7);
            asm volatile("s_waitcnt vmcnt(0)" ::: "memory");
            __builtin_amdgcn_sched_barrier(0);
            *(u32x4*)&Ws[HS_BASE + (st_p[0] * 16 + st_ch[0]) * WSROW + st_o16[0] * 8] = st0;
            *(u32x4*)&Ws[HS_BASE + (st_p[1] * 16 + st_ch[1]) * WSROW + st_o16[1] * 8] = st1;
            *(u32x4*)&Ws[HS_BASE + (st_p[2] * 16 + st_ch[2]) * WSROW + st_o16[2] * 8] = st2;
            *(u32x4*)&Ws[HS_BASE + (st_p[3] * 16 + st_ch[3]) * WSROW + st_o16[3] * 8] = st3;
            *(u32x4*)&Ws[HS_BASE + (st_p[4] * 16 + st_ch[4]) * WSROW + st_o16[4] * 8] = st4;
            *(u32x4*)&Ws[HS_BASE + (st_p[5] * 16 + st_ch[5]) * WSROW + st_o16[5] * 8] = st5;
            *(u32x4*)&Ws[HS_BASE + (st_p[6] * 16 + st_ch[6]) * WSROW + st_o16[6] * 8] = st6;
            *(u32x4*)&Ws[HS_BASE + (st_p[7] * 16 + st_ch[7]) * WSROW + st_o16[7] * 8] = st7;
        }
        __syncthreads();                                      // (2b) h staged in LDS

        // ================= proj (waves 0-2) =================
        if (wave < 3) {
            f32x4 accA = {0.f, 0.f, 0.f, 0.f}, accB = {0.f, 0.f, 0.f, 0.f};
            const int ha0 = HS_BASE + (0 * 16 + col) * WSROW;   // hi plane, chain=col
            const int ha1 = HS_BASE + (1 * 16 + col) * WSROW;   // lo plane
            #pragma unroll
            for (int kq = 0; kq < 16; ++kq) {
                const int ka = kq * 32 + quad * 8;
                bf16x8 ahv = *(const bf16x8*)&Ws[ha0 + ka];
                bf16x8 alv = *(const bf16x8*)&Ws[ha1 + ka];
                bf16x8 bh = *(const bf16x8*)&Ws[((0 * 3 + wave) * 16 + col) * WSROW + ka];
                bf16x8 bl = *(const bf16x8*)&Ws[((1 * 3 + wave) * 16 + col) * WSROW + ka];
                accA = __builtin_amdgcn_mfma_f32_16x16x32_bf16(ahv, bh, accA, 0, 0, 0);
                accB = __builtin_amdgcn_mfma_f32_16x16x32_bf16(ahv, bl, accB, 0, 0, 0);
                accA = __builtin_amdgcn_mfma_f32_16x16x32_bf16(alv, bh, accA, 0, 0, 0);
            }
            const f32x4 acc = accA + accB;
            // scatter: D col=lane&15 -> W-row j (h col n0+j); row quad*4+reg -> chain
            #pragma unroll
            for (int reg = 0; reg < 4; ++reg) {
                const int m = quad * 4 + reg;
                const int curm = s_cur[(m << 6) + t];
                HWC[(size_t)(m0 + m) * (SS * HH * 4) + (size_t)curm * 2048
                    + (n0 + col) * 4 + wave] = acc[reg];
            }
        }
        __threadfence_block();      // proj scatter -> next gates (same block)
        __syncthreads();            // (3)
        xp_c = xp_n;
    }
}

// ---------------------------------------------------------------------------
// Final projection: out[b,l] = hf32[b,:] . Wout[l,:] + bout[l]
// ---------------------------------------------------------------------------
__global__ __launch_bounds__(64) void out_kernel(
    const float* __restrict__ hcur,
    const float* __restrict__ Wout, const float* __restrict__ bout,
    float* __restrict__ out)
{
    const int b = blockIdx.x;
    const int lane = threadIdx.x;
    float acc[LL];
    #pragma unroll
    for (int l = 0; l < LL; ++l) acc[l] = 0.0f;
    for (int h = lane; h < HH; h += 64) {
        const float hv = hcur[(size_t)b * HH + h];
        #pragma unroll
        for (int l = 0; l < LL; ++l) acc[l] += hv * Wout[l * HH + h];
    }
    #pragma unroll
    for (int off = 32; off > 0; off >>= 1) {
        #pragma unroll
        for (int l = 0; l < LL; ++l) acc[l] += __shfl_down(acc[l], off);
    }
    if (lane == 0) {
        #pragma unroll
        for (int l = 0; l < LL; ++l) out[b * LL + l] = acc[l] + bout[l];
    }
}

extern "C" void kernel_launch(void* const* d_in, const int* in_sizes, int n_in,
                              void* d_out, int out_size, void* d_ws, size_t ws_size,
                              hipStream_t stream)
{
    (void)in_sizes; (void)n_in; (void)out_size; (void)ws_size;
    const int*   x        = (const int*)d_in[0];
    const int*   bfs      = (const int*)d_in[1];
    const int*   children = (const int*)d_in[2];
    const float* embed    = (const float*)d_in[3];
    const float* Wix = (const float*)d_in[4];
    const float* bix = (const float*)d_in[5];
    const float* Wih = (const float*)d_in[6];
    const float* bih = (const float*)d_in[7];
    const float* Wfx = (const float*)d_in[8];
    const float* bfx = (const float*)d_in[9];
    const float* Wfh = (const float*)d_in[10];
    const float* bfh = (const float*)d_in[11];
    const float* Wux = (const float*)d_in[12];
    const float* bux = (const float*)d_in[13];
    const float* Wuh = (const float*)d_in[14];
    const float* buh = (const float*)d_in[15];
    const float* Wout = (const float*)d_in[16];
    const float* bout = (const float*)d_in[17];
    float* out = (float*)d_out;

    // Workspace (~141 MB) — identical layout to the proven v4 kernel
    char* p = (char*)d_ws;
    float* XPp = (float*)p;            p += (size_t)BSH * 4 * 4;   // packed i,f,u,pad
    float* HWC = (float*)p;            p += (size_t)BSH * 4 * 4;   // packed HWi,HWf,HWu,C
    float* hf32 = (float*)p;           p += (size_t)BB * HH * 4;
    unsigned short* h_hi = (unsigned short*)p; p += (size_t)BB * HH * 2;
    unsigned short* h_lo = (unsigned short*)p; p += (size_t)BB * HH * 2;
    unsigned short* Wixh = (unsigned short*)p; p += (size_t)HH * KP * 2;
    unsigned short* Wixl = (unsigned short*)p; p += (size_t)HH * KP * 2;
    unsigned short* Wfxh = (unsigned short*)p; p += (size_t)HH * KP * 2;
    unsigned short* Wfxl = (unsigned short*)p; p += (size_t)HH * KP * 2;
    unsigned short* Wuxh = (unsigned short*)p; p += (size_t)HH * KP * 2;
    unsigned short* Wuxl = (unsigned short*)p; p += (size_t)HH * KP * 2;
    unsigned short* Wihh = (unsigned short*)p; p += (size_t)HH * HH * 2;
    unsigned short* Wihl = (unsigned short*)p; p += (size_t)HH * HH * 2;
    unsigned short* Wfhh = (unsigned short*)p; p += (size_t)HH * HH * 2;
    unsigned short* Wfhl = (unsigned short*)p; p += (size_t)HH * HH * 2;
    unsigned short* Wuhh = (unsigned short*)p; p += (size_t)HH * HH * 2;
    unsigned short* Wuhl = (unsigned short*)p; p += (size_t)HH * HH * 2;
    unsigned char* clist = (unsigned char*)p;  p += (size_t)BB * SS * SS;
    int* ccnt = (int*)p;               p += (size_t)BB * SS * 4;
    int* bars = (int*)p;               p += (size_t)NGRP * SS * 4;

    (void)hipFuncSetAttribute((const void*)fused_steps,
                              hipFuncAttributeMaxDynamicSharedMemorySize,
                              WS_BYTES);

    prep_kernel<<<dim3(256), 256, 0, stream>>>(
        bfs, children, Wix, Wfx, Wux, Wih, Wfh, Wuh,
        Wixh, Wixl, Wfxh, Wfxl, Wuxh, Wuxl,
        Wihh, Wihl, Wfhh, Wfhl, Wuhh, Wuhl, clist, ccnt, bars);

    xp_mfma<<<dim3(512, 3), 256, 0, stream>>>(
        x, embed, Wixh, Wixl, Wfxh, Wfxl, Wuxh, Wuxl,
        bix, bih, bfx, bfh, bux, buh, XPp);

    {
        void* args[] = {
            (void*)&bfs, (void*)&clist, (void*)&ccnt, (void*)&XPp,
            (void*)&Wihh, (void*)&Wihl, (void*)&Wfhh, (void*)&Wfhl,
            (void*)&Wuhh, (void*)&Wuhl,
            (void*)&HWC, (void*)&hf32, (void*)&h_hi, (void*)&h_lo, (void*)&bars
        };
        hipLaunchCooperativeKernel((void*)fused_steps, dim3(NGRP * BPG), dim3(256),
                                   args, WS_BYTES, stream);
    }

    out_kernel<<<dim3(BB), 64, 0, stream>>>(hf32, Wout, bout, out);
}